// Round 2
// 312.026 us; speedup vs baseline: 1.0159x; 1.0159x over previous
//
#include <hip/hip_runtime.h>

// Problem constants (match reference)
#define BATCH    64
#define HEIGHT   512
#define WIDTH    512
#define CHAN     3
#define PATCH    8
#define NPH      64
#define NPW      64
#define NP_TOT   4096          // NPH*NPW
#define NUM_MASK 3072          // 0.75 * NP_TOT

#define PER_IMG4 (HEIGHT * WIDTH * CHAN / 4)   // 196608 float4 per image
#define PER_ROW4 (WIDTH * CHAN / 4)            // 384 float4 per row
#define TOTAL4   (BATCH * PER_IMG4)            // 12,582,912 float4 total

// Native vector type for nontemporal builtins (HIP's float4 wrapper is
// rejected by __builtin_nontemporal_*; this ext_vector compiles to the same
// global_load_dwordx4 / global_store_dwordx4 with the nt cache hint).
typedef float f32x4 __attribute__((ext_vector_type(4)));

// Kernel 1 (merged init+scatter): one block per image.
//  - 256 threads vector-init the image's 4096-byte mask region to 1 (uint4 each)
//  - __syncthreads() (implies vmcnt drain -> block-visible via same-CU L2)
//  - each thread scatters 12 zero bytes at the image's masked patch indices.
// Indices within an image are a permutation prefix (distinct) -> race-free.
// (d_ws is re-poisoned to 0xAA before every launch, so init must run each call;
//  we do NOT rely on the poison value.)
__global__ __launch_bounds__(256) void rm_build_mask(
        const int* __restrict__ mask_indices,
        unsigned char* __restrict__ mask) {
    const int b = blockIdx.x;
    const int t = threadIdx.x;

    // init: 4096 B / image = 256 x uint4
    uint4 ones = make_uint4(0x01010101u, 0x01010101u, 0x01010101u, 0x01010101u);
    reinterpret_cast<uint4*>(mask + b * NP_TOT)[t] = ones;
    __syncthreads();

    // scatter: 3072 indices / 256 threads = 12 each, coalesced index reads
    const int* __restrict__ idx = mask_indices + b * NUM_MASK;
    unsigned char* __restrict__ m = mask + b * NP_TOT;
#pragma unroll
    for (int j = 0; j < 12; ++j) {
        m[idx[t + j * 256]] = (unsigned char)0;
    }
}

// Kernel 2: out = in * mask, one float4 per thread.
// 75% of patches are masked -> those lanes write zeros WITHOUT reading the
// input. The exec-masked global_load_dwordx4 only fetches active lanes'
// sectors: each 96 B patch row-segment touches exactly two 64 B sectors, so
// reads ~ 25% * 4/3 of the input (~67 MB). A patch covers 24 contiguous
// floats per row (6 float4), so each aligned float4 lies entirely within one
// patch -> one byte-mask lookup per 16 B (same L1 line across the wave).
// Non-temporal hints on the streaming in/out keep the hot 256 KB mask
// resident in cache while 384 MB streams past.
__global__ __launch_bounds__(256) void rm_apply_mask(
        const f32x4* __restrict__ in,
        f32x4* __restrict__ out,
        const unsigned char* __restrict__ mask) {
    const int tid = blockIdx.x * blockDim.x + threadIdx.x;
    const int b  = tid / PER_IMG4;
    const int r  = tid - b * PER_IMG4;
    const int y  = r / PER_ROW4;
    const int x4 = r - y * PER_ROW4;
    const int px = x4 / 6;          // 6 float4 per patch along x
    const int py = y >> 3;          // PATCH = 8 rows per patch
    const unsigned char m = mask[b * NP_TOT + (py << 6) + px];
    f32x4 v = (f32x4)(0.f, 0.f, 0.f, 0.f);
    if (m) v = __builtin_nontemporal_load(&in[tid]);  // masked lanes fetch nothing
    __builtin_nontemporal_store(v, &out[tid]);
}

extern "C" void kernel_launch(void* const* d_in, const int* in_sizes, int n_in,
                              void* d_out, int out_size, void* d_ws, size_t ws_size,
                              hipStream_t stream) {
    const float* images       = (const float*)d_in[0];
    const int*   mask_indices = (const int*)d_in[1];
    float*       out          = (float*)d_out;
    unsigned char* mask       = (unsigned char*)d_ws;   // 256 KB used

    // 1) mask := 1 then mask[b, idx] := 0   (one block per image)
    rm_build_mask<<<BATCH, 256, 0, stream>>>(mask_indices, mask);

    // 2) out = in * mask   (TOTAL4 is an exact multiple of 256)
    rm_apply_mask<<<TOTAL4 / 256, 256, 0, stream>>>(
        (const f32x4*)images, (f32x4*)out, mask);
}